// Round 7
// baseline (124.724 us; speedup 1.0000x reference)
//
#include <hip/hip_runtime.h>
#include <hip/hip_bf16.h>
#include <math.h>

#define B 4
#define S 2048
#define E 1024
#define A 128
#define CHUNK 256          // keys per split-K chunk
#define NCHMAX 8           // S / CHUNK
#define QBLK 128           // q-rows per attention block (8 waves)

typedef __attribute__((ext_vector_type(8))) short short8;   // 8 bf16 (4 VGPRs)
typedef __attribute__((ext_vector_type(4))) float floatx4;  // MFMA C/D

// fp32 -> bf16 scalar (RNE)
static __device__ __forceinline__ short f2bf(float f) {
  union { float f; unsigned u; } c;
  c.f = f;
  unsigned r = (c.u + 0x7fffu + ((c.u >> 16) & 1u)) >> 16;
  return (short)r;
}
// packed pair: 2 fp32 -> 2 bf16 in one uint (v_cvt_pk_bf16_f32)
static __device__ __forceinline__ unsigned f2bf2(float x, float y) {
  __hip_bfloat162 h = __float22bfloat162_rn(float2{x, y});
  union { __hip_bfloat162 h; unsigned u; } c;
  c.h = h;
  return c.u;
}

// ---------------------------------------------------------------------------
// Projection GEMM with fused W conversion + zero-init of the atomic
// accumulation buffers (Ounn/Ltot) — kernel-boundary ordering makes the
// zeros visible device-wide before attn_part's atomics. (R6-verified.)
// ---------------------------------------------------------------------------
__global__ __launch_bounds__(256) void proj_gemm(
    const float* __restrict__ X,
    const float* __restrict__ Wq,    // [A][E] f32
    const float* __restrict__ Wk,
    const float* __restrict__ Wv,
    short* __restrict__ Qbf,
    short* __restrict__ Kbf,
    short* __restrict__ Vt,
    float* __restrict__ Ounn,        // [B*S][A] zeroed here
    float* __restrict__ Ltot) {      // [B*S]   zeroed here
  __shared__ short As[64 * 64];
  __shared__ short Bs[128 * 64];

  const int m0 = blockIdx.x * 64;
  const int which = blockIdx.y;
  const float* Wpb = (which == 0) ? Wq : (which == 1) ? Wk : Wv;

  const int tid = threadIdx.x;

  // zero the atomic accumulators for this 64-row slice (which==0 blocks)
  if (which == 0) {
    const float4 z = {0.f, 0.f, 0.f, 0.f};
    float4* zb = (float4*)&Ounn[(size_t)m0 * A];    // 64*128 f32 = 2048 float4
#pragma unroll
    for (int i = 0; i < 8; ++i) zb[tid + i * 256] = z;
    if (tid < 64) Ltot[m0 + tid] = 0.f;
  }

  const int wave = tid >> 6;
  const int lane = tid & 63;
  const int mh = wave & 1;
  const int nh = wave >> 1;
  const int l16 = lane & 15;
  const int quad = lane >> 4;

  // staging geometry (constant per thread), with swizzled LDS offsets
  int xbase[4], wbase[4], aoff[4], boff[4];
#pragma unroll
  for (int i = 0; i < 4; ++i) {
    const int fa = tid + i * 256;          // 1024 float4 slots (64 rows x 16)
    const int arow = fa >> 4, ac4 = fa & 15;
    xbase[i] = (m0 + arow) * E + ac4 * 4;
    aoff[i] = arow * 64 + (((ac4 >> 1) ^ (arow & 7)) << 3) + ((ac4 & 1) << 2);
    const int fb = tid + i * 256;          // 1024 short8 slots (128 rows x 8)
    const int brow = fb >> 3, bc8 = fb & 7;
    wbase[i] = brow * E + bc8 * 8;         // in floats
    boff[i] = brow * 64 + ((bc8 ^ (brow & 7)) << 3);
  }

  // fragment-read bases (swizzled slot per thread)
  int arb[2], brb[4], swz[2];
#pragma unroll
  for (int ms = 0; ms < 2; ++ms) arb[ms] = (mh * 32 + ms * 16 + l16) * 64;
#pragma unroll
  for (int nt = 0; nt < 4; ++nt) brb[nt] = (nh * 64 + nt * 16 + l16) * 64;
#pragma unroll
  for (int ks = 0; ks < 2; ++ks) swz[ks] = (((ks * 4 + quad) ^ (l16 & 7)) << 3);

  floatx4 acc[2][4] = {};
  float4 apl0[4], apl1[4];
  float4 bpl0[4][2], bpl1[4][2];

  // prologue: preload k-tiles 0 and 64
#pragma unroll
  for (int i = 0; i < 4; ++i) {
    apl0[i] = *(const float4*)&X[xbase[i]];
    bpl0[i][0] = *(const float4*)&Wpb[wbase[i]];
    bpl0[i][1] = *(const float4*)&Wpb[wbase[i] + 4];
    apl1[i] = *(const float4*)&X[xbase[i] + 64];
    bpl1[i][0] = *(const float4*)&Wpb[wbase[i] + 64];
    bpl1[i][1] = *(const float4*)&Wpb[wbase[i] + 68];
  }

#define PROJ_BODY(APL, BPL, KNEXT)                                            \
  do {                                                                        \
    __syncthreads();                                                          \
    _Pragma("unroll") for (int i = 0; i < 4; ++i) {                           \
      uint2 pk; pk.x = f2bf2(APL[i].x, APL[i].y);                             \
      pk.y = f2bf2(APL[i].z, APL[i].w);                                       \
      *(uint2*)&As[aoff[i]] = pk;                                             \
      uint4 pb;                                                               \
      pb.x = f2bf2(BPL[i][0].x, BPL[i][0].y);                                 \
      pb.y = f2bf2(BPL[i][0].z, BPL[i][0].w);                                 \
      pb.z = f2bf2(BPL[i][1].x, BPL[i][1].y);                                 \
      pb.w = f2bf2(BPL[i][1].z, BPL[i][1].w);                                 \
      *(uint4*)&Bs[boff[i]] = pb;                                             \
    }                                                                         \
    __syncthreads();                                                          \
    if ((KNEXT) < E) {                                                        \
      _Pragma("unroll") for (int i = 0; i < 4; ++i) {                         \
        APL[i] = *(const float4*)&X[xbase[i] + (KNEXT)];                      \
        BPL[i][0] = *(const float4*)&Wpb[wbase[i] + (KNEXT)];                 \
        BPL[i][1] = *(const float4*)&Wpb[wbase[i] + (KNEXT) + 4];             \
      }                                                                       \
    }                                                                         \
    short8 afr[2][2], bfr[4][2];                                              \
    _Pragma("unroll") for (int ms = 0; ms < 2; ++ms)                          \
      _Pragma("unroll") for (int ks = 0; ks < 2; ++ks)                        \
        afr[ms][ks] = *(const short8*)&As[arb[ms] + swz[ks]];                 \
    _Pragma("unroll") for (int nt = 0; nt < 4; ++nt)                          \
      _Pragma("unroll") for (int ks = 0; ks < 2; ++ks)                        \
        bfr[nt][ks] = *(const short8*)&Bs[brb[nt] + swz[ks]];                 \
    _Pragma("unroll") for (int ms = 0; ms < 2; ++ms)                          \
      _Pragma("unroll") for (int nt = 0; nt < 4; ++nt)                        \
        _Pragma("unroll") for (int ks = 0; ks < 2; ++ks)                      \
          acc[ms][nt] = __builtin_amdgcn_mfma_f32_16x16x32_bf16(              \
              afr[ms][ks], bfr[nt][ks], acc[ms][nt], 0, 0, 0);                \
  } while (0)

  for (int k0 = 0; k0 < E; k0 += 128) {
    PROJ_BODY(apl0, bpl0, k0 + 128);
    PROJ_BODY(apl1, bpl1, k0 + 192);
  }
#undef PROJ_BODY

  const float qscale = 0.08838834764831845f;  // 1/sqrt(128)
#pragma unroll
  for (int ms = 0; ms < 2; ++ms) {
#pragma unroll
    for (int nt = 0; nt < 4; ++nt) {
      const int n = nh * 64 + nt * 16 + l16;
      const int mbase = m0 + mh * 32 + ms * 16 + quad * 4;   // + r
      if (which == 2) {
        const int b = mbase >> 11, s = mbase & (S - 1);
        short4 p;
        p.x = f2bf(acc[ms][nt][0]); p.y = f2bf(acc[ms][nt][1]);
        p.z = f2bf(acc[ms][nt][2]); p.w = f2bf(acc[ms][nt][3]);
        *(short4*)&Vt[((size_t)b * A + n) * S + s] = p;
      } else {
        short* Outp = (which == 0) ? Qbf : Kbf;
        const float sc = (which == 0) ? qscale : 1.0f;
#pragma unroll
        for (int r = 0; r < 4; ++r)
          Outp[(size_t)(mbase + r) * A + n] = f2bf(acc[ms][nt][r] * sc);
      }
    }
  }
}

// ---------------------------------------------------------------------------
// Flash-causal attention, split-K, QBLK=128 (8 waves / 512 threads):
// each 64-key staging step now serves 128 q-rows instead of 64 — total
// staging steps 2112 -> 1088, staged bytes 35 -> 18 MB, barrier events
// halved per unit work; per-block chain stays <= 4 steps (CHUNK=256).
// LDS 48 KB (Ks 16 + Vs 16 + Ps 8x2), same 16B-slot XOR swizzles.
// Epilogue: atomic fp32 accumulation (R6-verified); nch==1 tiles write
// Out directly.
// ---------------------------------------------------------------------------
__global__ __launch_bounds__(512) void attn_part(
    const short* __restrict__ Qbf,
    const short* __restrict__ Kbf,
    const short* __restrict__ Vt,
    float* __restrict__ Ounn,     // [B*S][A] atomic accum
    float* __restrict__ Ltot,     // [B*S]   atomic accum
    float* __restrict__ Out) {    // [B,S,A] direct write for nch==1
  __shared__ short Ks[64 * 128];      // [key][a], swizzled
  __shared__ short Vs[128 * 64];      // [a][key], swizzled
  __shared__ short Ps[8][16 * 64];    // per-wave [row][key], swizzled

  const int rev = (int)gridDim.x - 1 - (int)blockIdx.x;   // heavy-first
  const int qt = rev >> 3;            // 0..63  (128-row q-tiles)
  const int chunk = rev & 7;
  const int b = qt >> 4;
  const int q0 = (qt & 15) << 7;
  const int nk = q0 + QBLK;           // causal limit
  const int kstart = chunk * CHUNK;
  if (kstart >= nk) return;
  const int kend = min(kstart + CHUNK, nk);
  const int nch = (nk + CHUNK - 1) / CHUNK;

  const int tid = threadIdx.x;
  const int wave = tid >> 6;          // 0..7
  const int lane = tid & 63;
  const int l16 = lane & 15;
  const int quad = lane >> 4;

  // staging geometry: global bases + swizzled LDS write offsets (2 slots/thr)
  int kgb[2], vgb[2], kwoff[2], vwoff[2];
#pragma unroll
  for (int i = 0; i < 2; ++i) {
    const int f = tid + i * 512;
    const int krow = f >> 4, kc8 = f & 15;    // 64 rows x 16 slots
    kgb[i] = krow * A + kc8 * 8;
    kwoff[i] = krow * 128 + ((kc8 ^ (krow & 7)) << 3);
    const int vrow = f >> 3, vc8 = f & 7;     // 128 rows x 8 slots
    vgb[i] = vrow * S + vc8 * 8;
    vwoff[i] = vrow * 64 + ((vc8 ^ (vrow & 7)) << 3);
  }

  // swizzled fragment-read slot offsets (ks = 0..3 for K, 0..1 for V/P)
  int swz[4];
#pragma unroll
  for (int ks = 0; ks < 4; ++ks) swz[ks] = (((ks * 4 + quad) ^ (l16 & 7)) << 3);

  // Ps swizzled write offsets: row = quad*4+r, col = nt*16+l16
  int pwoff[4][4];
#pragma unroll
  for (int nt = 0; nt < 4; ++nt)
#pragma unroll
    for (int r = 0; r < 4; ++r) {
      const int row = quad * 4 + r;
      const int slot = nt * 2 + (l16 >> 3);
      pwoff[nt][r] = row * 64 + ((slot ^ (row & 7)) << 3) + (l16 & 7);
    }

  // Q A-fragments (wave w owns q-rows q0 + w*16 .. +15)
  short8 qfr[4];
  {
    const size_t qrow = (size_t)(b * S + q0 + wave * 16 + l16);
#pragma unroll
    for (int ks = 0; ks < 4; ++ks)
      qfr[ks] = *(const short8*)&Qbf[qrow * A + ks * 32 + quad * 8];
  }

  float l_acc[4] = {0.f, 0.f, 0.f, 0.f};
  floatx4 oacc[8] = {};

  const int myrow = q0 + wave * 16 + quad * 4;      // + r
  const short* Kbase = Kbf + (size_t)b * S * A;
  const short* Vbase = Vt + (size_t)b * A * S;

  short8 kplf[2], vplf[2];
  // prologue: load first tile
#pragma unroll
  for (int i = 0; i < 2; ++i) {
    kplf[i] = *(const short8*)&Kbase[kstart * A + kgb[i]];
    vplf[i] = *(const short8*)&Vbase[vgb[i] + kstart];
  }

  for (int j0 = kstart; j0 < kend; j0 += 64) {
    __syncthreads();                 // prev iter's LDS consumers done
#pragma unroll
    for (int i = 0; i < 2; ++i) {
      *(short8*)&Ks[kwoff[i]] = kplf[i];
      *(short8*)&Vs[vwoff[i]] = vplf[i];
    }
    __syncthreads();                 // staging visible

    // prefetch next tile (waited on at next iter's ds_write)
    if (j0 + 64 < kend) {
#pragma unroll
      for (int i = 0; i < 2; ++i) {
        kplf[i] = *(const short8*)&Kbase[(j0 + 64) * A + kgb[i]];
        vplf[i] = *(const short8*)&Vbase[vgb[i] + j0 + 64];
      }
    }

    // ---- S = Q.K^T  (4 n-tiles of 16 keys) ----
    floatx4 sc[4];
#pragma unroll
    for (int nt = 0; nt < 4; ++nt) {
      floatx4 c = {};
#pragma unroll
      for (int ks = 0; ks < 4; ++ks) {
        const short8 bfr = *(const short8*)&Ks[(nt * 16 + l16) * 128 + swz[ks]];
        c = __builtin_amdgcn_mfma_f32_16x16x32_bf16(qfr[ks], bfr, c, 0, 0, 0);
      }
      sc[nt] = c;
    }

    // ---- mask + exp (no max-sub), accumulate l ----
#pragma unroll
    for (int nt = 0; nt < 4; ++nt) {
      const int key = j0 + nt * 16 + l16;
#pragma unroll
      for (int r = 0; r < 4; ++r) {
        const float p = (key > myrow + r) ? 0.f : __expf(sc[nt][r]);
        sc[nt][r] = p;
        l_acc[r] += p;
      }
    }

    // ---- P -> wave-private LDS -> A-operand layout ----
#pragma unroll
    for (int nt = 0; nt < 4; ++nt)
#pragma unroll
      for (int r = 0; r < 4; ++r)
        Ps[wave][pwoff[nt][r]] = f2bf(sc[nt][r]);

    short8 pfr[2];
#pragma unroll
    for (int ks = 0; ks < 2; ++ks)
      pfr[ks] = *(const short8*)&Ps[wave][l16 * 64 + swz[ks]];

    // ---- O += P.V  (8 a-tiles x 2 k-steps of 32 keys) ----
#pragma unroll
    for (int nt = 0; nt < 8; ++nt) {
#pragma unroll
      for (int ks = 0; ks < 2; ++ks) {
        const short8 vfr = *(const short8*)&Vs[(nt * 16 + l16) * 64 + swz[ks]];
        oacc[nt] = __builtin_amdgcn_mfma_f32_16x16x32_bf16(pfr[ks], vfr, oacc[nt], 0, 0, 0);
      }
    }
  }

  // ---- epilogue ----
  const int lr = wave * 16 + quad * 4;   // + r
  float lsum[4];
#pragma unroll
  for (int r = 0; r < 4; ++r) {
    float l = l_acc[r];
    l += __shfl_xor(l, 1);
    l += __shfl_xor(l, 2);
    l += __shfl_xor(l, 4);
    l += __shfl_xor(l, 8);
    lsum[r] = l;                       // all 16 lanes of the group hold it
  }

  if (nch == 1) {
    // single-chunk tile: normalize in-register, write Out directly
    float inv4[4];
#pragma unroll
    for (int r = 0; r < 4; ++r) inv4[r] = 1.f / lsum[r];
    float* o = Out + (size_t)(b * S + q0 + lr) * A;
#pragma unroll
    for (int nt = 0; nt < 8; ++nt)
#pragma unroll
      for (int r = 0; r < 4; ++r)
        o[(size_t)r * A + nt * 16 + l16] = oacc[nt][r] * inv4[r];
    return;
  }

  // atomic accumulation (device-scope fp32 adds; no ordering needed)
  float* orow = Ounn + (size_t)(b * S + q0 + lr) * A;
#pragma unroll
  for (int nt = 0; nt < 8; ++nt)
#pragma unroll
    for (int r = 0; r < 4; ++r)
      atomicAdd(&orow[(size_t)r * A + nt * 16 + l16], oacc[nt][r]);

  if (l16 == 0) {
#pragma unroll
    for (int r = 0; r < 4; ++r)
      atomicAdd(&Ltot[b * S + q0 + lr + r], lsum[r]);
  }
}

// ---------------------------------------------------------------------------
// Phase B: normalize Ounn by Ltot (only for q-tiles with nch>=2).
// 512 blocks of 16 rows — latency-bound, fill the CUs.
// ---------------------------------------------------------------------------
__global__ __launch_bounds__(256) void attn_reduce(
    const float* __restrict__ Ounn,
    const float* __restrict__ Ltot,
    float* __restrict__ Out) {
  const int g = blockIdx.x >> 2;      // 0..127 (64-row groups)
  const int quarter = blockIdx.x & 3;
  const int b = g >> 5;
  const int q0 = (g & 31) << 6;
  // 128-row q-tile index and its chunk count
  const int i128 = (g & 31) >> 1;
  const int nch = (i128 * QBLK + QBLK + CHUNK - 1) / CHUNK;
  if (nch == 1) return;               // attn_part wrote Out directly

  const int tid = threadIdx.x;
  const int lr = quarter * 16 + (tid >> 4);   // 0..63
  const int c0 = (tid & 15) * 8;              // 16 threads/row x 8 cols

  const size_t row = (size_t)(b * S + q0 + lr);
  const float inv = 1.f / Ltot[row];

  const float4* src = (const float4*)(Ounn + row * A + c0);
  float4* o = (float4*)(Out + row * A + c0);
#pragma unroll
  for (int i = 0; i < 2; ++i) {
    float4 v = src[i];
    v.x *= inv; v.y *= inv; v.z *= inv; v.w *= inv;
    o[i] = v;
  }
}

extern "C" void kernel_launch(void* const* d_in, const int* in_sizes, int n_in,
                              void* d_out, int out_size, void* d_ws, size_t ws_size,
                              hipStream_t stream) {
  const float* X  = (const float*)d_in[0];  // embedded [B,S,E]
  const float* Wk = (const float*)d_in[1];  // [A,E]
  const float* Wq = (const float*)d_in[2];
  const float* Wv = (const float*)d_in[3];
  float* Out = (float*)d_out;               // [B,S,A]

  const size_t qkv_elems = (size_t)B * S * A;   // 1M elems, bf16 -> 2MB each
  short* Qbf = (short*)d_ws;
  short* Kbf = Qbf + qkv_elems;
  short* Vt  = Kbf + qkv_elems;
  float* Ounn = (float*)(Vt + qkv_elems);           // B*S*A f32 = 4MB
  float* Ltot = Ounn + qkv_elems;                   // B*S f32 = 32KB

  dim3 pgrid(B * S / 64, 3);
  proj_gemm<<<pgrid, 256, 0, stream>>>(X, Wq, Wk, Wv, Qbf, Kbf, Vt, Ounn, Ltot);
  attn_part<<<(B * S / QBLK) * NCHMAX, 512, 0, stream>>>(Qbf, Kbf, Vt, Ounn, Ltot, Out);
  attn_reduce<<<B * S / 64 * 4, 256, 0, stream>>>(Ounn, Ltot, Out);
}